// Round 2
// baseline (59.332 us; speedup 1.0000x reference)
//
#include <hip/hip_runtime.h>

// Problem constants (hard-coded by the reference)
#define BATCH 32
#define HH 512
#define WW 512
#define ROWF (WW * 3)    // 1536 floats per image row
#define ROW4 (ROWF / 4)  // 384 float4 per image row
#define EPS 0.1f

__global__ __launch_bounds__(512)
void gnllt_kernel(const float* __restrict__ x,
                  const float* __restrict__ A,
                  const float* __restrict__ Bm,
                  const float* __restrict__ Cm,
                  const float* __restrict__ bias,
                  const float* __restrict__ wk,
                  float* __restrict__ out)
{
    __shared__ float lds[3][ROWF];   // rows h-1, h, h+1 (wrapped), flat-staged
    __shared__ float ldso[ROWF];     // output row staging for coalesced stores

    const int t  = threadIdx.x;              // 0..511
    const int bh = blockIdx.x;               // b*H + h
    const int h  = bh & (HH - 1);
    const int b  = bh >> 9;                  // /512
    const int hm = (h + HH - 1) & (HH - 1);
    const int hp = (h + 1) & (HH - 1);

    const size_t base = (size_t)b * HH * ROWF;
    const float4* rm4 = (const float4*)(x + base + (size_t)hm * ROWF);
    const float4* rc4 = (const float4*)(x + base + (size_t)h  * ROWF);
    const float4* rp4 = (const float4*)(x + base + (size_t)hp * ROWF);

    // Vectorized staging: 3 rows = 1152 float4, flat over 512 threads.
    // Flat index i -> row r = i/384, col = i - 384*r (unrolled by hand).
    float4* lds4 = (float4*)&lds[0][0];
    lds4[t]        = (t < 384) ? rm4[t]       : rc4[t - 384];
    lds4[t + 512]  = (t < 256) ? rc4[t + 128] : rp4[t - 256];
    if (t < 128)
        lds4[t + 1024] = rp4[t + 256];

    // Uniform (scalar) loads of the tiny parameter tensors.
    const float wv = wk[0];  // all K*K*C entries equal 1/27
    const float a00 = A[0],  a11 = A[4],  a22 = A[8];
    const float a01 = A[1] + A[3], a02 = A[2] + A[6], a12 = A[5] + A[7];
    const float b00 = Bm[0], b11 = Bm[4], b22 = Bm[8];
    const float b01 = Bm[1] + Bm[3], b02 = Bm[2] + Bm[6], b12 = Bm[5] + Bm[7];
    const float c00 = Cm[0], c11 = Cm[4], c22 = Cm[8];
    const float c01 = Cm[1] + Cm[3], c02 = Cm[2] + Cm[6], c12 = Cm[5] + Cm[7];
    const float bi0 = bias[0], bi1 = bias[1], bi2 = bias[2];

    __syncthreads();

    const int w  = t;
    const int wm = (w + WW - 1) & (WW - 1);
    const int wp = (w + 1) & (WW - 1);

    float s0 = 0.f, s1 = 0.f, s2 = 0.f;
    #pragma unroll
    for (int r = 0; r < 3; ++r) {
        s0 += lds[r][wm * 3 + 0] + lds[r][w * 3 + 0] + lds[r][wp * 3 + 0];
        s1 += lds[r][wm * 3 + 1] + lds[r][w * 3 + 1] + lds[r][wp * 3 + 1];
        s2 += lds[r][wm * 3 + 2] + lds[r][w * 3 + 2] + lds[r][wp * 3 + 2];
    }
    const float x0 = s0 * wv, x1 = s1 * wv, x2 = s2 * wv;

    const float p00 = x0 * x0, p11 = x1 * x1, p22 = x2 * x2;
    const float p01 = x0 * x1, p02 = x0 * x2, p12 = x1 * x2;

    const float d0 = bi0 + a00 * p00 + a11 * p11 + a22 * p22
                         + a01 * p01 + a02 * p02 + a12 * p12;
    const float d1 = bi1 + b00 * p00 + b11 * p11 + b22 * p22
                         + b01 * p01 + b02 * p02 + b12 * p12;
    const float d2 = bi2 + c00 * p00 + c11 * p11 + c22 * p22
                         + c01 * p01 + c02 * p02 + c12 * p12;

    // Stage result in LDS, then store the row as coalesced float4.
    ldso[w * 3 + 0] = lds[1][w * 3 + 0] + EPS * d0;
    ldso[w * 3 + 1] = lds[1][w * 3 + 1] + EPS * d1;
    ldso[w * 3 + 2] = lds[1][w * 3 + 2] + EPS * d2;

    __syncthreads();

    if (t < ROW4) {
        float4* o4 = (float4*)(out + base + (size_t)h * ROWF);
        o4[t] = ((const float4*)ldso)[t];
    }
}

extern "C" void kernel_launch(void* const* d_in, const int* in_sizes, int n_in,
                              void* d_out, int out_size, void* d_ws, size_t ws_size,
                              hipStream_t stream) {
    const float* x    = (const float*)d_in[0];
    const float* A    = (const float*)d_in[1];
    const float* Bm   = (const float*)d_in[2];
    const float* Cm   = (const float*)d_in[3];
    const float* bias = (const float*)d_in[4];
    const float* wk   = (const float*)d_in[5];
    float* out = (float*)d_out;

    dim3 grid(BATCH * HH);   // one block per (b, h) row
    dim3 block(512);
    gnllt_kernel<<<grid, block, 0, stream>>>(x, A, Bm, Cm, bias, wk, out);
}

// Round 3
// 47.571 us; speedup vs baseline: 1.2472x; 1.2472x over previous
//
#include <hip/hip_runtime.h>

// B=32, H=W=512, C=3, toroidal 3x3 uniform depthwise avg + per-pixel quadratic forms.
#define HH 512
#define ROW4 384            // float4 per image row (512*3/4)
#define RPW 8               // rows per wave
#define EPS 0.1f

__device__ __forceinline__ void load_hsum(const float4* __restrict__ rp,
                                          const int* c, float* S, float* rawdst) {
    // g[m] = row[12*t - 4 + m], m = 0..19 (t = lane's first own f4 / 3)
    float4 F0 = rp[c[0]], F1 = rp[c[1]], F2 = rp[c[2]], F3 = rp[c[3]], F4 = rp[c[4]];
    float g[20] = {F0.x,F0.y,F0.z,F0.w, F1.x,F1.y,F1.z,F1.w, F2.x,F2.y,F2.z,F2.w,
                   F3.x,F3.y,F3.z,F3.w, F4.x,F4.y,F4.z,F4.w};
    // hsum for own 4 px, 3 ch: hs[3j+c] = x[px-1..px+1] channel sum
    #pragma unroll
    for (int q = 0; q < 12; ++q) S[q] = g[1+q] + g[4+q] + g[7+q];
    if (rawdst) {
        #pragma unroll
        for (int q = 0; q < 12; ++q) rawdst[q] = g[4+q];   // own 12 floats
    }
}

__global__ __launch_bounds__(256)
void gnllt_kernel(const float* __restrict__ xin,
                  const float* __restrict__ A,
                  const float* __restrict__ Bm,
                  const float* __restrict__ Cm,
                  const float* __restrict__ bias,
                  const float* __restrict__ wk,
                  float* __restrict__ outp)
{
    const int lane  = threadIdx.x & 63;
    const int wid   = (blockIdx.x << 2) | (threadIdx.x >> 6);
    const int strip = wid & 1;            // two 256-px strips per row
    const int grp   = wid >> 1;           // 0..2047
    const int img   = grp >> 6;           // 0..31
    const int h0    = (grp & 63) * RPW;   // 0..504

    // Uniform parameter loads -> SGPRs. Fold eps * wv^2 into quad coeffs.
    const float wv = wk[0];
    const float qs = EPS * wv * wv;
    const float qa00 = qs*A[0],  qa11 = qs*A[4],  qa22 = qs*A[8];
    const float qa01 = qs*(A[1]+A[3]),  qa02 = qs*(A[2]+A[6]),  qa12 = qs*(A[5]+A[7]);
    const float qb00 = qs*Bm[0], qb11 = qs*Bm[4], qb22 = qs*Bm[8];
    const float qb01 = qs*(Bm[1]+Bm[3]), qb02 = qs*(Bm[2]+Bm[6]), qb12 = qs*(Bm[5]+Bm[7]);
    const float qc00 = qs*Cm[0], qc11 = qs*Cm[4], qc22 = qs*Cm[8];
    const float qc01 = qs*(Cm[1]+Cm[3]), qc02 = qs*(Cm[2]+Cm[6]), qc12 = qs*(Cm[5]+Cm[7]);
    const float bi0 = EPS*bias[0], bi1 = EPS*bias[1], bi2 = EPS*bias[2];

    const float4* x4 = (const float4*)xin;
    float4*       o4 = (float4*)outp;

    // f4-column indices for the 5 overlapping loads (wrap within row)
    const int cb = strip * 192 + 3 * lane;     // first own f4 in row
    int c[5];
    #pragma unroll
    for (int j = 0; j < 5; ++j) {
        int v = cb - 1 + j;
        if (v < 0)     v += ROW4;
        if (v >= ROW4) v -= ROW4;
        c[j] = v;
    }
    const size_t ib = (size_t)img * (HH * ROW4);

    float hs[3][12];    // rolling horizontal-sum rows (compile-time phase indices)
    float raw[12];      // raw row h (for output)
    float rawN[12];     // raw row h+1 in flight

    // Prime: rows h0-1 and h0
    load_hsum(x4 + ib + (size_t)((h0 + HH - 1) & (HH - 1)) * ROW4, c, hs[0], nullptr);
    load_hsum(x4 + ib + (size_t)h0 * ROW4,                         c, hs[1], raw);

    #pragma unroll
    for (int i = 0; i < RPW; ++i) {
        const int r = (h0 + 1 + i) & (HH - 1);
        load_hsum(x4 + ib + (size_t)r * ROW4, c, hs[(2 + i) % 3], rawN);

        const float* hm = hs[i % 3];
        const float* hc = hs[(i + 1) % 3];
        const float* hp = hs[(i + 2) % 3];

        float of[12];
        #pragma unroll
        for (int j = 0; j < 4; ++j) {
            const float s0 = hm[3*j+0] + hc[3*j+0] + hp[3*j+0];
            const float s1 = hm[3*j+1] + hc[3*j+1] + hp[3*j+1];
            const float s2 = hm[3*j+2] + hc[3*j+2] + hp[3*j+2];
            const float p00 = s0*s0, p11 = s1*s1, p22 = s2*s2;
            const float p01 = s0*s1, p02 = s0*s2, p12 = s1*s2;
            of[3*j+0] = raw[3*j+0] + bi0 + qa00*p00 + qa11*p11 + qa22*p22
                                        + qa01*p01 + qa02*p02 + qa12*p12;
            of[3*j+1] = raw[3*j+1] + bi1 + qb00*p00 + qb11*p11 + qb22*p22
                                        + qb01*p01 + qb02*p02 + qb12*p12;
            of[3*j+2] = raw[3*j+2] + bi2 + qc00*p00 + qc11*p11 + qc22*p22
                                        + qc01*p01 + qc02*p02 + qc12*p12;
        }

        float4* op = o4 + ib + (size_t)(h0 + i) * ROW4 + cb;
        op[0] = make_float4(of[0], of[1], of[2],  of[3]);
        op[1] = make_float4(of[4], of[5], of[6],  of[7]);
        op[2] = make_float4(of[8], of[9], of[10], of[11]);

        #pragma unroll
        for (int q = 0; q < 12; ++q) raw[q] = rawN[q];
    }
}

extern "C" void kernel_launch(void* const* d_in, const int* in_sizes, int n_in,
                              void* d_out, int out_size, void* d_ws, size_t ws_size,
                              hipStream_t stream) {
    const float* x    = (const float*)d_in[0];
    const float* A    = (const float*)d_in[1];
    const float* Bm   = (const float*)d_in[2];
    const float* Cm   = (const float*)d_in[3];
    const float* bias = (const float*)d_in[4];
    const float* wk   = (const float*)d_in[5];
    float* out = (float*)d_out;

    // 32 imgs x 64 row-groups x 2 strips = 4096 waves = 1024 blocks of 4 waves
    dim3 grid(1024);
    dim3 block(256);
    gnllt_kernel<<<grid, block, 0, stream>>>(x, A, Bm, Cm, bias, wk, out);
}